// Round 1
// baseline (995.927 us; speedup 1.0000x reference)
//
#include <hip/hip_runtime.h>
#include <math.h>

typedef unsigned short u16;
typedef __attribute__((ext_vector_type(8))) short short8;
typedef __attribute__((ext_vector_type(4))) float floatx4;

__device__ __forceinline__ u16 f2bf(float f) {
    union { float f; unsigned u; } v; v.f = f;
    unsigned r = v.u + 0x7fffu + ((v.u >> 16) & 1u);
    return (u16)(r >> 16);
}

struct WPtrs {
    const float* w1[5];
    const float* b1[5];
    const float* w2[5];
};

// ---------------- prep: transpose + pad weights to bf16 ----------------
// W1t: [head][n][k] 5*256*256 bf16 (W1t[h][n][k] = W1_h[k][n], zero-padded)
// W2t: rows (mask@0 x16, pos@16 x16, scl@32 x16, rot@48 x16, shs@64 x48) * 256k
// b1p: [head][n] 5*256 fp32, col 255 zero
__global__ void prep_weights(WPtrs p, u16* __restrict__ W1t,
                             u16* __restrict__ W2t, float* __restrict__ b1p)
{
    int gid = blockIdx.x * 256 + threadIdx.x;
    if (gid < 5 * 256 * 256) {
        int h   = gid >> 16;
        int rem = gid & 65535;
        int nn  = rem >> 8;
        int k   = rem & 255;
        float v = (nn < 255 && k < 255) ? p.w1[h][k * 255 + nn] : 0.0f;
        W1t[gid] = f2bf(v);
    }
    if (gid < 112 * 256) {
        int row = gid >> 8;
        int k   = gid & 255;
        int h, roff, od;
        if (row < 16)      { h = 0; roff = 0;  od = 1; }
        else if (row < 32) { h = 1; roff = 16; od = 3; }
        else if (row < 48) { h = 2; roff = 32; od = 3; }
        else if (row < 64) { h = 3; roff = 48; od = 4; }
        else               { h = 4; roff = 64; od = 48; }
        int nn = row - roff;
        float v = (k < 255 && nn < od) ? p.w2[h][k * od + nn] : 0.0f;
        W2t[gid] = f2bf(v);
    }
    if (gid < 5 * 256) {
        int h  = gid >> 8;
        int nn = gid & 255;
        b1p[gid] = (nn < 255) ? p.b1[h][nn] : 0.0f;
    }
}

// ---------------- build x = relu(concat(features)) bf16, cols padded to 256 ----------------
__global__ void build_x(const float* __restrict__ opa, const float* __restrict__ shs,
                        const float* __restrict__ te,  const float* __restrict__ sem,
                        const float* __restrict__ pt,  const float* __restrict__ scl,
                        const float* __restrict__ rot, const float* __restrict__ dx,
                        u16* __restrict__ x, int n)
{
    int row = blockIdx.x;
    if (row >= n) return;
    int c = threadIdx.x;
    float v;
    if (c < 3)        v = pt[row * 3 + c];
    else if (c < 7)   v = rot[row * 4 + (c - 3)];
    else if (c < 10)  v = scl[row * 3 + (c - 7)];
    else if (c < 11)  v = opa[row];
    else if (c < 59)  v = shs[(size_t)row * 48 + (c - 11)];
    else if (c < 187) v = sem[(size_t)row * 128 + (c - 59)];
    else if (c < 190) v = dx[row * 3 + (c - 187)];
    else if (c < 191) v = te[row];
    else if (c < 255) {
        int j = c - 191;                 // 0..63, pairs (sin,cos)
        float t = te[0];
        float fi = (float)(j & ~1);      // 2*(j>>1)
        float freq = powf(10000.0f, fi * (1.0f / 32.0f));
        float a = t / freq;
        v = (j & 1) ? cosf(a) : sinf(a);
    } else v = 0.0f;
    x[(size_t)row * 256 + c] = f2bf(fmaxf(v, 0.0f));
}

// ---------------- fused 5-head MLP ----------------
// block = 64 rows, 4 waves; wave w owns rows [16w,16w+16) (full K for its rows).
// LDS union: phase1 staging A(64x72 bf16 @0, 9216B) + B(256x72 bf16 @9216, 36864B)
//            phase2 H (4 wave regions of 16x264 bf16, 33792B @0) -- barrier-guarded reuse
//            mask_lds: 64 fp32 @46080
template<int NCT>
__device__ __forceinline__ void run_head(
    const u16* __restrict__ x, const u16* __restrict__ W1t_h,
    const u16* __restrict__ W2t_r, const float* __restrict__ b1_h,
    u16* A_lds, u16* B_lds, u16* Hw,
    int rowbase, int wrow, int q, int ln, int tid,
    floatx4* acc2)
{
    floatx4 acc[16];
#pragma unroll
    for (int i = 0; i < 16; ++i) acc[i] = (floatx4){0.f, 0.f, 0.f, 0.f};

#pragma unroll
    for (int ks = 0; ks < 4; ++ks) {
        const int k0 = ks * 64;
        // stage A: 64 rows x 64 k (2 x 16B chunks / thread)
#pragma unroll
        for (int i = 0; i < 2; ++i) {
            int c = tid + i * 256;
            int lr = c >> 3, cc = c & 7;
            short8 v = *(const short8*)(x + (size_t)(rowbase + lr) * 256 + k0 + cc * 8);
            *(short8*)&A_lds[lr * 72 + cc * 8] = v;
        }
        // stage B (W1t rows = output cols): 256 n x 64 k (8 chunks / thread)
#pragma unroll
        for (int i = 0; i < 8; ++i) {
            int c = tid + i * 256;
            int nn = c >> 3, cc = c & 7;
            short8 v = *(const short8*)(W1t_h + nn * 256 + k0 + cc * 8);
            *(short8*)&B_lds[nn * 72 + cc * 8] = v;
        }
        __syncthreads();
#pragma unroll
        for (int kk = 0; kk < 2; ++kk) {
            short8 a = *(short8*)&A_lds[(wrow + ln) * 72 + kk * 32 + q * 8];
#pragma unroll
            for (int ct = 0; ct < 16; ++ct) {
                short8 b = *(short8*)&B_lds[(ct * 16 + ln) * 72 + kk * 32 + q * 8];
                acc[ct] = __builtin_amdgcn_mfma_f32_16x16x32_bf16(a, b, acc[ct], 0, 0, 0);
            }
        }
        __syncthreads();   // last iter: also guards H overlay below
    }
    // h1 = relu(acc + b1) -> Hw (bf16), wave-private region
#pragma unroll
    for (int ct = 0; ct < 16; ++ct) {
        float b1v = b1_h[ct * 16 + ln];
#pragma unroll
        for (int r = 0; r < 4; ++r) {
            float v = acc[ct][r] + b1v;
            Hw[(q * 4 + r) * 264 + ct * 16 + ln] = f2bf(fmaxf(v, 0.0f));
        }
    }
    __syncthreads();
    // phase 2: out = h1 @ W2 ; B-frags straight from global (L1/L2-resident)
#pragma unroll
    for (int i = 0; i < NCT; ++i) acc2[i] = (floatx4){0.f, 0.f, 0.f, 0.f};
#pragma unroll
    for (int ks = 0; ks < 8; ++ks) {
        short8 a2 = *(short8*)&Hw[ln * 264 + ks * 32 + q * 8];
#pragma unroll
        for (int c2 = 0; c2 < NCT; ++c2) {
            short8 b2 = *(const short8*)(W2t_r + (c2 * 16 + ln) * 256 + ks * 32 + q * 8);
            acc2[c2] = __builtin_amdgcn_mfma_f32_16x16x32_bf16(a2, b2, acc2[c2], 0, 0, 0);
        }
    }
    __syncthreads();   // guard before next head restages over H
}

__global__ __launch_bounds__(256, 2) void fused_heads(
    const u16* __restrict__ x, const u16* __restrict__ W1t,
    const u16* __restrict__ W2t, const float* __restrict__ b1p,
    const float* __restrict__ b2m, const float* __restrict__ b2p,
    const float* __restrict__ b2s, const float* __restrict__ b2r,
    const float* __restrict__ b2h,
    const float* __restrict__ pt, const float* __restrict__ scl,
    const float* __restrict__ rot, const float* __restrict__ shs,
    const float* __restrict__ opa, float* __restrict__ out, int n)
{
    __shared__ __attribute__((aligned(16))) char smem[46336];
    u16* A_lds = (u16*)smem;
    u16* B_lds = (u16*)(smem + 9216);
    u16* H_lds = (u16*)smem;
    float* mask_lds = (float*)(smem + 46080);

    const int tid  = threadIdx.x;
    const int wave = tid >> 6;
    const int lane = tid & 63;
    const int q    = lane >> 4;
    const int ln   = lane & 15;
    const int rowbase = blockIdx.x * 64;
    const int wrow = wave * 16;
    u16* Hw = H_lds + wave * (16 * 264);
    const size_t NN = (size_t)n;

    floatx4 acc2[3];

    // ---- head 0: mask (sigmoid) + opacity copy ----
    run_head<1>(x, W1t, W2t, b1p, A_lds, B_lds, Hw, rowbase, wrow, q, ln, tid, acc2);
    {
        const int grow0 = rowbase + wrow + q * 4;
        if (ln == 0) {
            float bb = b2m[0];
#pragma unroll
            for (int r = 0; r < 4; ++r) {
                float raw = acc2[0][r] + bb;
                mask_lds[wrow + q * 4 + r] = 1.0f / (1.0f + expf(-raw));
            }
        }
        if (ln == 1) {
#pragma unroll
            for (int r = 0; r < 4; ++r) {
                int grow = grow0 + r;
                out[10 * NN + grow] = opa[grow];
            }
        }
    }
    __syncthreads();
    float maskv[4];
#pragma unroll
    for (int r = 0; r < 4; ++r) maskv[r] = mask_lds[wrow + q * 4 + r];

    // ---- head 1: pos -> dx_out + pts ----
    run_head<1>(x, W1t + 1 * 65536, W2t + 16 * 256, b1p + 1 * 256,
                A_lds, B_lds, Hw, rowbase, wrow, q, ln, tid, acc2);
    if (ln < 3) {
        float bb = b2p[ln];
#pragma unroll
        for (int r = 0; r < 4; ++r) {
            int grow = rowbase + wrow + q * 4 + r;
            float raw = acc2[0][r] + bb;
            out[59 * NN + (size_t)grow * 3 + ln] = raw;
            out[(size_t)grow * 3 + ln] = pt[(size_t)grow * 3 + ln] + raw * maskv[r];
        }
    }

    // ---- head 2: scl -> scales ----
    run_head<1>(x, W1t + 2 * 65536, W2t + 32 * 256, b1p + 2 * 256,
                A_lds, B_lds, Hw, rowbase, wrow, q, ln, tid, acc2);
    if (ln < 3) {
        float bb = b2s[ln];
#pragma unroll
        for (int r = 0; r < 4; ++r) {
            int grow = rowbase + wrow + q * 4 + r;
            float raw = acc2[0][r] + bb;
            out[3 * NN + (size_t)grow * 3 + ln] = scl[(size_t)grow * 3 + ln] + raw * maskv[r];
        }
    }

    // ---- head 3: rot -> rotations ----
    run_head<1>(x, W1t + 3 * 65536, W2t + 48 * 256, b1p + 3 * 256,
                A_lds, B_lds, Hw, rowbase, wrow, q, ln, tid, acc2);
    if (ln < 4) {
        float bb = b2r[ln];
#pragma unroll
        for (int r = 0; r < 4; ++r) {
            int grow = rowbase + wrow + q * 4 + r;
            float raw = acc2[0][r] + bb;
            out[6 * NN + (size_t)grow * 4 + ln] = rot[(size_t)grow * 4 + ln] + raw * maskv[r];
        }
    }

    // ---- head 4: shs -> dshs + shs ----
    run_head<3>(x, W1t + 4 * 65536, W2t + 64 * 256, b1p + 4 * 256,
                A_lds, B_lds, Hw, rowbase, wrow, q, ln, tid, acc2);
#pragma unroll
    for (int c2 = 0; c2 < 3; ++c2) {
        int n2 = c2 * 16 + ln;   // 0..47
        float bb = b2h[n2];
#pragma unroll
        for (int r = 0; r < 4; ++r) {
            int grow = rowbase + wrow + q * 4 + r;
            float raw = acc2[c2][r] + bb;
            out[62 * NN + (size_t)grow * 48 + n2] = raw;
            out[11 * NN + (size_t)grow * 48 + n2] = shs[(size_t)grow * 48 + n2] + raw * maskv[r];
        }
    }
}

extern "C" void kernel_launch(void* const* d_in, const int* in_sizes, int n_in,
                              void* d_out, int out_size, void* d_ws, size_t ws_size,
                              hipStream_t stream)
{
    const float* opa  = (const float*)d_in[0];
    const float* shs  = (const float*)d_in[1];
    const float* te   = (const float*)d_in[2];
    const float* sem  = (const float*)d_in[3];
    const float* pt   = (const float*)d_in[4];
    const float* scl  = (const float*)d_in[5];
    const float* rot  = (const float*)d_in[6];
    const float* dx   = (const float*)d_in[7];

    WPtrs p;
    p.w1[0] = (const float*)d_in[8];  p.b1[0] = (const float*)d_in[9];  p.w2[0] = (const float*)d_in[10];
    p.w1[1] = (const float*)d_in[12]; p.b1[1] = (const float*)d_in[13]; p.w2[1] = (const float*)d_in[14];
    p.w1[2] = (const float*)d_in[16]; p.b1[2] = (const float*)d_in[17]; p.w2[2] = (const float*)d_in[18];
    p.w1[3] = (const float*)d_in[20]; p.b1[3] = (const float*)d_in[21]; p.w2[3] = (const float*)d_in[22];
    p.w1[4] = (const float*)d_in[24]; p.b1[4] = (const float*)d_in[25]; p.w2[4] = (const float*)d_in[26];
    const float* b2m = (const float*)d_in[11];
    const float* b2p = (const float*)d_in[15];
    const float* b2s = (const float*)d_in[19];
    const float* b2r = (const float*)d_in[23];
    const float* b2h = (const float*)d_in[27];

    const int n = in_sizes[0];               // 200000 (divisible by 64)

    // workspace layout (total ~98.3 MB)
    char* ws = (char*)d_ws;
    u16* x   = (u16*)ws;                                   // n*256 bf16
    u16* W1t = (u16*)(ws + (size_t)n * 256 * 2);           // 5*256*256 bf16
    u16* W2t = W1t + 5 * 256 * 256;                        // 112*256 bf16
    float* b1p = (float*)(W2t + 112 * 256);                // 5*256 fp32

    prep_weights<<<1280, 256, 0, stream>>>(p, W1t, W2t, b1p);
    build_x<<<n, 256, 0, stream>>>(opa, shs, te, sem, pt, scl, rot, dx, x, n);
    fused_heads<<<n / 64, 256, 0, stream>>>(x, W1t, W2t, b1p,
                                            b2m, b2p, b2s, b2r, b2h,
                                            pt, scl, rot, shs, opa,
                                            (float*)d_out, n);
}